// Round 2
// baseline (313.578 us; speedup 1.0000x reference)
//
#include <hip/hip_runtime.h>

// Problem constants
constexpr int Bb = 16;      // batch
constexpr int Nn = 256;     // regions
constexpr int Hh = 768;     // hidden
constexpr int Pp = 2048;    // proj dim
constexpr int Rr = 3;       // relation types
constexpr int Mm = Bb * Nn; // 4096 flattened rows
constexpr int HA = 896;     // augmented hidden (768 + 1 bias row + pad)
constexpr int KA = 2080;    // augmented K for Bop GEMM (2048 + 32)
constexpr int JA = Rr * HA; // 2688

typedef __bf16 bf16_t;
typedef __bf16 bf16x8 __attribute__((ext_vector_type(8)));
typedef __bf16 bf16x4 __attribute__((ext_vector_type(4)));
typedef float  floatx4 __attribute__((ext_vector_type(4)));

// async global->LDS, 16B per lane; LDS dest = wave-uniform base + lane*16
__device__ __forceinline__ void gld_lds16(const void* g, void* l) {
    __builtin_amdgcn_global_load_lds(
        (__attribute__((address_space(1))) void*)g,
        (__attribute__((address_space(3))) void*)l,
        16, 0, 0);
}

// Counted-vmcnt wait (keeps younger prefetches in flight across the barrier).
#define WAIT_VMCNT(n) asm volatile("s_waitcnt vmcnt(" #n ")" ::: "memory")

// Raw barrier WITHOUT the compiler's vmcnt(0) drain (__syncthreads would drain
// the whole prefetch queue). sched_barrier(0) + mem-clobber fence pin motion.
__device__ __forceinline__ void pipe_barrier() {
    __builtin_amdgcn_s_barrier();
    __builtin_amdgcn_sched_barrier(0);
    asm volatile("" ::: "memory");
}

// ---------------------------------------------------------------------------
// F_aug [4096, 896] bf16: cols 0..767 = F, col 768 = 1, cols 769..895 = 0
// ---------------------------------------------------------------------------
__global__ __launch_bounds__(256) void build_Faug(
    const float* __restrict__ F, bf16_t* __restrict__ out)
{
    const int idx = blockIdx.x * 256 + threadIdx.x;   // over 4096 * (896/4)
    const int n = idx / (HA / 4), c4 = idx % (HA / 4);
    const int h = c4 * 4;
    bf16x4 o;
    if (h < Hh) {
        float4 v = *(const float4*)(F + (size_t)n * Hh + h);
        o = { (bf16_t)v.x, (bf16_t)v.y, (bf16_t)v.z, (bf16_t)v.w };
    } else {
        #pragma unroll
        for (int e = 0; e < 4; ++e) o[e] = (bf16_t)((h + e == Hh) ? 1.0f : 0.0f);
    }
    *(bf16x4*)(out + (size_t)n * HA + h) = o;
}

// ---------------------------------------------------------------------------
// tWaug [896, 2048]: rows j<768 = tW^T (tW[q,j]), row 768 = bt[q], rows>768 = 0
// ---------------------------------------------------------------------------
__global__ __launch_bounds__(256) void build_tWaug(
    const float* __restrict__ tW, const float* __restrict__ bt,
    bf16_t* __restrict__ out)
{
    __shared__ float t[32][33];
    const int j0 = blockIdx.y * 32, q0 = blockIdx.x * 32;
    const int tx = threadIdx.x, ty = threadIdx.y;
    #pragma unroll
    for (int s = 0; s < 4; ++s) {
        const int q = q0 + ty + s * 8, j = j0 + tx;
        t[ty + s * 8][tx] = (j < Hh) ? tW[(size_t)q * Hh + j] : 0.0f;
    }
    __syncthreads();
    #pragma unroll
    for (int s = 0; s < 4; ++s) {
        const int j = j0 + ty + s * 8, q = q0 + tx;
        float v = t[tx][ty + s * 8];
        if (j == Hh) v = bt[q];
        else if (j > Hh) v = 0.0f;
        out[(size_t)j * Pp + q] = (bf16_t)v;
    }
}

// ---------------------------------------------------------------------------
// hWaug [896, 2080]: rows h<768 = hW^T, row 768 = [bh | 1 @ p=2048], rows>768=0
// ---------------------------------------------------------------------------
__global__ __launch_bounds__(256) void build_hWaug(
    const float* __restrict__ hW, const float* __restrict__ bh,
    bf16_t* __restrict__ out)
{
    __shared__ float t[32][33];
    const int h0 = blockIdx.y * 32, p0 = blockIdx.x * 32;
    const int tx = threadIdx.x, ty = threadIdx.y;
    #pragma unroll
    for (int s = 0; s < 4; ++s) {
        const int p = p0 + ty + s * 8, h = h0 + tx;
        t[ty + s * 8][tx] = (p < Pp && h < Hh) ? hW[(size_t)p * Hh + h] : 0.0f;
    }
    __syncthreads();
    #pragma unroll
    for (int s = 0; s < 4; ++s) {
        const int h = h0 + ty + s * 8, p = p0 + tx;
        float v = t[tx][ty + s * 8];
        if (h == Hh) v = (p < Pp) ? bh[p] : (p == Pp ? 1.0f : 0.0f);
        else if (h > Hh) v = 0.0f;
        out[(size_t)h * KA + p] = (bf16_t)v;
    }
}

// ---------------------------------------------------------------------------
// fill T1taug col stripe [j][2048..2079]: col 2048 = (j==768 ? bil_b[r] : 0)
// ---------------------------------------------------------------------------
__global__ __launch_bounds__(256) void fill_T1cols(
    const float* __restrict__ bil_b, bf16_t* __restrict__ T1)
{
    const int idx = blockIdx.x * 256 + threadIdx.x;
    if (idx >= Rr * HA) return;
    const int r = idx / HA, j = idx % HA;
    bf16_t* p = T1 + (size_t)r * HA * KA + (size_t)j * KA + Pp;
    p[0] = (bf16_t)(j == Hh ? bil_b[r] : 0.0f);
    #pragma unroll
    for (int e = 1; e < 32; ++e) p[e] = (bf16_t)0.0f;
}

// ---------------------------------------------------------------------------
// 128(M)x64(N)-tile NT GEMM, A bf16 / B fp32 (in-kernel cvt),
// 4-deep LDS multibuffer with counted vmcnt (prefetch distance 3):
// per-step the barrier waits only for the tile about to be consumed
// (vmcnt(2L)); tiles k+1,k+2 stay in flight across the barrier. This is the
// T3/T4 mechanism — the depth-1 __syncthreads version drained vmcnt(0) every
// 32-K step and exposed full HBM/L3 latency (MfmaUtil 12%, 300 TF).
//   C[m,n] = sum_k A[m,k] * B[n,k];  T1 = tWaug @ bil_W[r]^T
// grid (N/64, M/128, R).  L = 4 loads/wave/tile -> waits 8/4/0.
// ---------------------------------------------------------------------------
__global__ __launch_bounds__(256) void gemm_nt_128x64_bf32(
    const bf16_t* __restrict__ A, int lda,
    const float*  __restrict__ B, int ldb, size_t sB,
    bf16_t* __restrict__ C, int ldc, size_t sC, int K)
{
    B += (size_t)blockIdx.z * sB;
    C += (size_t)blockIdx.z * sC;

    __shared__ bf16_t As[4][128 * 32];   // 8 KB per buf (32 KB)
    __shared__ float  Bs[4][64 * 32];    // 8 KB per buf (32 KB)

    const int tid = threadIdx.x;
    const int w = tid >> 6;
    const int l = tid & 63;
    const int m0 = blockIdx.y * 128;
    const int n0 = blockIdx.x * 64;

    // A staging (bf16, 128x32 = 8KB, 2 issues): row = i*64 + w*16 + l/4
    const bf16_t* ga0 = A + (size_t)(m0 + (w << 4) + (l >> 2)) * lda + ((l & 3) << 3);
    const bf16_t* ga1 = ga0 + (size_t)64 * lda;
    // B staging (fp32, 64x32 = 8KB, 2 issues), swizzled: physical col-group
    // (l&7) holds global col-group (l&7)^(row&7); row = i*32 + w*8 + l/8,
    // so row&7 = l>>3 for both issues.
    const int brow = (w << 3) + (l >> 3);
    const int bgrp = (l & 7) ^ (l >> 3);
    const float* gb0 = B + (size_t)(n0 + brow) * ldb + (bgrp << 2);
    const float* gb1 = gb0 + (size_t)32 * ldb;

    const int wm = (w >> 1) << 6;    // wave M-offset: 0/64
    const int wn = (w & 1) << 5;     // wave N-offset: 0/32
    const int fr = l & 15;
    const int fq = (l >> 4) << 3;

    // swizzled fragment-read col offsets (floats); row&7 == fr&7
    const int swz = fr & 7;
    const int cg0 = (l >> 4) << 1;
    const int off0 = ((cg0 ^ swz) << 2);
    const int off1 = (((cg0 + 1) ^ swz) << 2);

    floatx4 acc[4][2] = {};

    // prologue: tiles 0,1,2 in flight (12 loads/wave)
    #pragma unroll
    for (int t = 0; t < 3; ++t) {
        gld_lds16(ga0, (char*)As[t] + (w << 10));
        gld_lds16(ga1, (char*)As[t] + 4096 + (w << 10));
        gld_lds16(gb0, (char*)Bs[t] + (w << 10));
        gld_lds16(gb1, (char*)Bs[t] + 4096 + (w << 10));
        ga0 += 32; ga1 += 32; gb0 += 32; gb1 += 32;
    }

    const int steps = K >> 5;   // 64
    for (int k = 0; k < steps; ++k) {
        if (k + 2 < steps)      WAIT_VMCNT(8);   // tile k landed; k+1,k+2 fly
        else if (k + 1 < steps) WAIT_VMCNT(4);
        else                    WAIT_VMCNT(0);
        pipe_barrier();

        const int cur = k & 3;
        if (k + 3 < steps) {
            const int nxt = (k + 3) & 3;
            gld_lds16(ga0, (char*)As[nxt] + (w << 10));
            gld_lds16(ga1, (char*)As[nxt] + 4096 + (w << 10));
            gld_lds16(gb0, (char*)Bs[nxt] + (w << 10));
            gld_lds16(gb1, (char*)Bs[nxt] + 4096 + (w << 10));
            ga0 += 32; ga1 += 32; gb0 += 32; gb1 += 32;
        }

        bf16x8 a[4], b[2];
        #pragma unroll
        for (int i = 0; i < 4; ++i)
            a[i] = *(const bf16x8*)&As[cur][(wm + i * 16 + fr) * 32 + fq];
        #pragma unroll
        for (int j = 0; j < 2; ++j) {
            const float* bp = &Bs[cur][(wn + j * 16 + fr) * 32];
            floatx4 x0 = *(const floatx4*)(bp + off0);
            floatx4 x1 = *(const floatx4*)(bp + off1);
            #pragma unroll
            for (int e = 0; e < 4; ++e) { b[j][e] = (bf16_t)x0[e]; b[j][e + 4] = (bf16_t)x1[e]; }
        }
        #pragma unroll
        for (int i = 0; i < 4; ++i)
            #pragma unroll
            for (int j = 0; j < 2; ++j)
                acc[i][j] = __builtin_amdgcn_mfma_f32_16x16x32_bf16(a[i], b[j], acc[i][j], 0, 0, 0);
    }

    const int em = m0 + wm + ((l >> 4) << 2);
    const int en = n0 + wn + (l & 15);
    #pragma unroll
    for (int i = 0; i < 4; ++i)
        #pragma unroll
        for (int j = 0; j < 2; ++j)
            #pragma unroll
            for (int rg = 0; rg < 4; ++rg)
                C[(size_t)(em + i * 16 + rg) * ldc + en + j * 16] = (bf16_t)acc[i][j][rg];
}

// ---------------------------------------------------------------------------
// 64x64-tile bf16 NT GEMM, 4-deep multibuffer, counted vmcnt (for Bop)
// L = 2 loads/wave/tile -> waits 4/2/0
// ---------------------------------------------------------------------------
__global__ __launch_bounds__(256) void gemm_nt_64(
    const bf16_t* __restrict__ A, int lda, size_t sA,
    const bf16_t* __restrict__ B, int ldb, size_t sB,
    bf16_t* __restrict__ C, int ldc, size_t sC, int K)
{
    A += (size_t)blockIdx.z * sA;
    B += (size_t)blockIdx.z * sB;
    C += (size_t)blockIdx.z * sC;

    __shared__ bf16_t As[4][64 * 32];   // 4 KB per buf
    __shared__ bf16_t Bs[4][64 * 32];

    const int tid = threadIdx.x;
    const int w = tid >> 6;
    const int l = tid & 63;
    const int m0 = blockIdx.y * 64;
    const int n0 = blockIdx.x * 64;

    const bf16_t* ga = A + (size_t)(m0 + (tid >> 2)) * lda + ((tid & 3) << 3);
    const bf16_t* gb = B + (size_t)(n0 + (tid >> 2)) * ldb + ((tid & 3) << 3);

    const int wm = (w >> 1) << 5;
    const int wn = (w & 1) << 5;
    const int fr = l & 15;
    const int fq = (l >> 4) << 3;

    floatx4 acc[2][2] = {};

    #pragma unroll
    for (int t = 0; t < 3; ++t) {
        gld_lds16(ga, (char*)As[t] + (w << 10));
        gld_lds16(gb, (char*)Bs[t] + (w << 10));
        ga += 32; gb += 32;
    }

    const int steps = K >> 5;   // 65
    for (int k = 0; k < steps; ++k) {
        if (k + 2 < steps)      WAIT_VMCNT(4);
        else if (k + 1 < steps) WAIT_VMCNT(2);
        else                    WAIT_VMCNT(0);
        pipe_barrier();

        const int cur = k & 3;
        if (k + 3 < steps) {
            const int nxt = (k + 3) & 3;
            gld_lds16(ga, (char*)As[nxt] + (w << 10));
            gld_lds16(gb, (char*)Bs[nxt] + (w << 10));
            ga += 32; gb += 32;
        }

        bf16x8 a[2], b[2];
        #pragma unroll
        for (int i = 0; i < 2; ++i) {
            a[i] = *(const bf16x8*)&As[cur][(wm + i * 16 + fr) * 32 + fq];
            b[i] = *(const bf16x8*)&Bs[cur][(wn + i * 16 + fr) * 32 + fq];
        }
        #pragma unroll
        for (int i = 0; i < 2; ++i)
            #pragma unroll
            for (int j = 0; j < 2; ++j)
                acc[i][j] = __builtin_amdgcn_mfma_f32_16x16x32_bf16(a[i], b[j], acc[i][j], 0, 0, 0);
    }

    const int em = m0 + wm + ((l >> 4) << 2);
    const int en = n0 + wn + (l & 15);
    #pragma unroll
    for (int i = 0; i < 2; ++i)
        #pragma unroll
        for (int j = 0; j < 2; ++j)
            #pragma unroll
            for (int rg = 0; rg < 4; ++rg)
                C[(size_t)(em + i * 16 + rg) * ldc + en + j * 16] = (bf16_t)acc[i][j][rg];
}

// ---------------------------------------------------------------------------
// 128x128-tile bf16 NT GEMM, 4-deep multibuffer, counted vmcnt (for FG)
// L = 4 loads/wave/tile -> waits 8/4/0
// ---------------------------------------------------------------------------
__global__ __launch_bounds__(256) void gemm_nt_128(
    const bf16_t* __restrict__ A, int lda,
    const bf16_t* __restrict__ B, int ldb,
    bf16_t* __restrict__ C, int ldc, int K)
{
    __shared__ bf16_t As[4][128 * 32];   // 32 KB
    __shared__ bf16_t Bs[4][128 * 32];   // 32 KB

    const int tid = threadIdx.x;
    const int w = tid >> 6;
    const int l = tid & 63;
    const int m0 = blockIdx.y * 128;
    const int n0 = blockIdx.x * 128;

    const int srow = (w << 4) + (l >> 2);
    const int scol = (l & 3) << 3;
    const bf16_t* ga0 = A + (size_t)(m0 + srow) * lda + scol;
    const bf16_t* ga1 = ga0 + (size_t)64 * lda;
    const bf16_t* gb0 = B + (size_t)(n0 + srow) * ldb + scol;
    const bf16_t* gb1 = gb0 + (size_t)64 * ldb;

    const int wm = (w >> 1) << 6;
    const int wn = (w & 1) << 6;
    const int fr = l & 15;
    const int fq = (l >> 4) << 3;

    floatx4 acc[4][4] = {};

    #pragma unroll
    for (int t = 0; t < 3; ++t) {
        char* a = (char*)As[t] + (w << 10);
        char* b = (char*)Bs[t] + (w << 10);
        gld_lds16(ga0, a); gld_lds16(ga1, a + 4096);
        gld_lds16(gb0, b); gld_lds16(gb1, b + 4096);
        ga0 += 32; ga1 += 32; gb0 += 32; gb1 += 32;
    }

    const int steps = K >> 5;   // 28
    for (int k = 0; k < steps; ++k) {
        if (k + 2 < steps)      WAIT_VMCNT(8);
        else if (k + 1 < steps) WAIT_VMCNT(4);
        else                    WAIT_VMCNT(0);
        pipe_barrier();

        const int cur = k & 3;
        if (k + 3 < steps) {
            const int nxt = (k + 3) & 3;
            char* a = (char*)As[nxt] + (w << 10);
            char* b = (char*)Bs[nxt] + (w << 10);
            gld_lds16(ga0, a); gld_lds16(ga1, a + 4096);
            gld_lds16(gb0, b); gld_lds16(gb1, b + 4096);
            ga0 += 32; ga1 += 32; gb0 += 32; gb1 += 32;
        }

        bf16x8 a[4], b[4];
        #pragma unroll
        for (int i = 0; i < 4; ++i) {
            a[i] = *(const bf16x8*)&As[cur][(wm + i * 16 + fr) * 32 + fq];
            b[i] = *(const bf16x8*)&Bs[cur][(wn + i * 16 + fr) * 32 + fq];
        }
        #pragma unroll
        for (int i = 0; i < 4; ++i)
            #pragma unroll
            for (int j = 0; j < 4; ++j)
                acc[i][j] = __builtin_amdgcn_mfma_f32_16x16x32_bf16(a[i], b[j], acc[i][j], 0, 0, 0);
    }

    const int em = m0 + wm + ((l >> 4) << 2);
    const int en = n0 + wn + (l & 15);
    #pragma unroll
    for (int j = 0; j < 4; ++j) {
        const int n = en + j * 16;
        #pragma unroll
        for (int i = 0; i < 4; ++i) {
            #pragma unroll
            for (int rg = 0; rg < 4; ++rg)
                C[(size_t)(em + i * 16 + rg) * ldc + n] = (bf16_t)(acc[i][j][rg]);
        }
    }
}

// ---------------------------------------------------------------------------
// fused output GEMM, all 3 r per block, 4-deep multibuffer, counted vmcnt.
// K=896, 512 threads; wave = 32n x 16m, 6 MFMA/step.
//   logits[b,n,m,r] = sum_h FG[b*Nn+n, r*HA+h] * Faug[b*Nn+m, h]
// grid (Nn/64, Nn/64, Bb) = 256 blocks.  L = 2 -> waits 4/2/0
// ---------------------------------------------------------------------------
__global__ __launch_bounds__(512) void gemm_out_fused(
    const bf16_t* __restrict__ FG,    // [Mm, JA]
    const bf16_t* __restrict__ FA,    // [Mm, HA]
    float* __restrict__ OUT)
{
    __shared__ bf16_t S[4][4][64 * 32];  // per buf: tiles 0..2 = FG r, 3 = Faug

    const int b = blockIdx.z;
    const int n0 = blockIdx.y * 64;
    const int m0 = blockIdx.x * 64;

    const int tid = threadIdx.x;
    const int w = tid >> 6;      // 0..7
    const int l = tid & 63;

    // staging: 16KB/step over 512 lanes = 2 issues of 16B.
    // issue i, wave w covers LDS bytes i*8192 + w*1024 + l*16
    //   -> tile = 2i + (w>>2), row = (w&3)*16 + l/4, col8 = (l&3)*8
    const int srow = ((w & 3) << 4) + (l >> 2);
    const int scol = (l & 3) << 3;
    const int t0 = w >> 2;               // issue0 tile: FG r = 0/1
    const bf16_t* g0 = FG + (size_t)(b * Nn + n0 + srow) * JA + t0 * HA + scol;
    const bf16_t* g1 = (t0 == 0)
        ? FG + (size_t)(b * Nn + n0 + srow) * JA + 2 * HA + scol   // tile2: FG r=2
        : FA + (size_t)(b * Nn + m0 + srow) * HA + scol;           // tile3: Faug

    const int n_off = (w >> 2) << 5;     // 0/32
    const int m_off = (w & 3) << 4;      // 0/16/32/48
    const int fr = l & 15;
    const int fq = (l >> 4) << 3;

    floatx4 acc[Rr][2] = {};

    #pragma unroll
    for (int t = 0; t < 3; ++t) {
        char* base = (char*)&S[t][0][0];
        gld_lds16(g0, base + (w << 10));        g0 += 32;
        gld_lds16(g1, base + 8192 + (w << 10)); g1 += 32;
    }

    constexpr int STEPS = HA / 32; // 28
    for (int k = 0; k < STEPS; ++k) {
        if (k + 2 < STEPS)      WAIT_VMCNT(4);
        else if (k + 1 < STEPS) WAIT_VMCNT(2);
        else                    WAIT_VMCNT(0);
        pipe_barrier();

        const int cur = k & 3;
        if (k + 3 < STEPS) {
            char* base = (char*)&S[(k + 3) & 3][0][0];
            gld_lds16(g0, base + (w << 10));        g0 += 32;
            gld_lds16(g1, base + 8192 + (w << 10)); g1 += 32;
        }

        bf16x8 t = *(const bf16x8*)&S[cur][3][(m_off + fr) * 32 + fq];
        #pragma unroll
        for (int r = 0; r < Rr; ++r) {
            #pragma unroll
            for (int i = 0; i < 2; ++i) {
                bf16x8 a = *(const bf16x8*)&S[cur][r][(n_off + i * 16 + fr) * 32 + fq];
                acc[r][i] = __builtin_amdgcn_mfma_f32_16x16x32_bf16(a, t, acc[r][i], 0, 0, 0);
            }
        }
    }

    const int en_ = n0 + n_off + ((l >> 4) << 2);
    const int em_ = m0 + m_off + (l & 15);
    #pragma unroll
    for (int i = 0; i < 2; ++i)
        #pragma unroll
        for (int rg = 0; rg < 4; ++rg) {
            const int n = en_ + i * 16 + rg;
            float* o = OUT + (((size_t)b * Nn + n) * Nn + em_) * Rr;
            #pragma unroll
            for (int r = 0; r < Rr; ++r)
                o[r] = acc[r][i][rg];
        }
}

extern "C" void kernel_launch(void* const* d_in, const int* in_sizes, int n_in,
                              void* d_out, int out_size, void* d_ws, size_t ws_size,
                              hipStream_t stream) {
    const float* features = (const float*)d_in[0]; // [16,256,768]
    const float* head_W   = (const float*)d_in[1]; // [2048,768]
    const float* head_b   = (const float*)d_in[2]; // [2048]
    const float* tail_W   = (const float*)d_in[3]; // [2048,768]
    const float* tail_b   = (const float*)d_in[4]; // [2048]
    const float* bil_W    = (const float*)d_in[5]; // [3,2048,2048]
    const float* bil_b    = (const float*)d_in[6]; // [3]
    float* out = (float*)d_out;                    // [16,256,256,3]

    // workspace layout (bf16), total ~52 MB
    char* ws = (char*)d_ws;
    bf16_t* Faug   = (bf16_t*)ws;  ws += (size_t)Mm * HA * 2;       // 7.3 MB
    bf16_t* tWaug  = (bf16_t*)ws;  ws += (size_t)HA * Pp * 2;       // 3.7 MB
    bf16_t* hWaug  = (bf16_t*)ws;  ws += (size_t)HA * KA * 2;       // 3.7 MB
    bf16_t* T1taug = (bf16_t*)ws;  ws += (size_t)Rr * HA * KA * 2;  // 11.2 MB
    bf16_t* Bop    = (bf16_t*)ws;  ws += (size_t)Rr * HA * HA * 2;  // 4.8 MB
    bf16_t* FG     = (bf16_t*)ws;  ws += (size_t)Mm * JA * 2;       // 22.0 MB

    // 1) build augmented operands (tiny/streaming; bil_W is consumed fp32-direct)
    build_Faug<<<Mm * (HA / 4) / 256, 256, 0, stream>>>(features, Faug);
    build_tWaug<<<dim3(Pp / 32, HA / 32), dim3(32, 8), 0, stream>>>(tail_W, tail_b, tWaug);
    build_hWaug<<<dim3(KA / 32, HA / 32), dim3(32, 8), 0, stream>>>(head_W, head_b, hWaug);

    // 2) T1taug[r] [896, 2048(+32)] = tWaug [896,2048] @ bil_W[r]^T (B fp32 direct)
    gemm_nt_128x64_bf32<<<dim3(Pp / 64, HA / 128, Rr), 256, 0, stream>>>(
        tWaug, Pp,
        bil_W, Pp, (size_t)Pp * Pp,
        T1taug, KA, (size_t)HA * KA, Pp);
    fill_T1cols<<<(Rr * HA + 255) / 256, 256, 0, stream>>>(bil_b, T1taug);

    // 3) Bop[r] [896, 896] = T1taug[r] [896,2080] @ hWaug^T [896,2080]
    gemm_nt_64<<<dim3(HA / 64, HA / 64, Rr), 256, 0, stream>>>(
        T1taug, KA, (size_t)HA * KA,
        hWaug, KA, 0,
        Bop, HA, (size_t)HA * HA, KA);

    // 4) FG [4096, 2688] = Faug [4096,896] @ Bop^T [2688,896]
    gemm_nt_128<<<dim3(JA / 128, Mm / 128), 256, 0, stream>>>(
        Faug, HA,
        Bop, HA,
        FG, JA, HA);

    // 5) fused output GEMM over all r (K=896, biases already folded in)
    gemm_out_fused<<<dim3(Nn / 64, Nn / 64, Bb), 512, 0, stream>>>(FG, Faug, out);
}

// Round 3
// 265.329 us; speedup vs baseline: 1.1818x; 1.1818x over previous
//
#include <hip/hip_runtime.h>

// Problem constants
constexpr int Bb = 16;      // batch
constexpr int Nn = 256;     // regions
constexpr int Hh = 768;     // hidden
constexpr int Pp = 2048;    // proj dim
constexpr int Rr = 3;       // relation types
constexpr int Mm = Bb * Nn; // 4096 flattened rows
constexpr int HA = 896;     // augmented hidden (768 + 1 bias row + pad)
constexpr int KA = 2112;    // augmented K for Bop GEMM (2048 + 64, BK=64 multiple)
constexpr int JA = Rr * HA; // 2688

typedef __bf16 bf16_t;
typedef __bf16 bf16x8 __attribute__((ext_vector_type(8)));
typedef __bf16 bf16x4 __attribute__((ext_vector_type(4)));
typedef float  floatx4 __attribute__((ext_vector_type(4)));

// async global->LDS, 16B per lane; LDS dest = wave-uniform base + lane*16
__device__ __forceinline__ void gld_lds16(const void* g, void* l) {
    __builtin_amdgcn_global_load_lds(
        (__attribute__((address_space(1))) void*)g,
        (__attribute__((address_space(3))) void*)l,
        16, 0, 0);
}

// ---------------------------------------------------------------------------
// BK=64 LDS tile conventions (bf16): tile [rows][64] bf16, 128B rows.
// 16B-group g within a row is XOR-swizzled: physical group p holds global
// cols (p ^ (row&7))*8 .. +7.  Staged via gld_lds16 with PRE-SWIZZLED global
// source col (LDS dest stays linear): lane l of wave w writes row
// (i*32 + w*8 + (l>>3)), phys group (l&7), so src col = ((l&7)^(l>>3))*8.
// Fragment read for K-half kk, lane (fr=l&15, hi=l>>4):
//   elem_off = row*64 + (((kk*4+hi) ^ (fr&7)) << 3)
// ---------------------------------------------------------------------------

// ---------------------------------------------------------------------------
// F_aug [4096, 896] bf16: cols 0..767 = F, col 768 = 1, cols 769..895 = 0
// ---------------------------------------------------------------------------
__global__ __launch_bounds__(256) void build_Faug(
    const float* __restrict__ F, bf16_t* __restrict__ out)
{
    const int idx = blockIdx.x * 256 + threadIdx.x;   // over 4096 * (896/4)
    const int n = idx / (HA / 4), c4 = idx % (HA / 4);
    const int h = c4 * 4;
    bf16x4 o;
    if (h < Hh) {
        float4 v = *(const float4*)(F + (size_t)n * Hh + h);
        o = { (bf16_t)v.x, (bf16_t)v.y, (bf16_t)v.z, (bf16_t)v.w };
    } else {
        #pragma unroll
        for (int e = 0; e < 4; ++e) o[e] = (bf16_t)((h + e == Hh) ? 1.0f : 0.0f);
    }
    *(bf16x4*)(out + (size_t)n * HA + h) = o;
}

// ---------------------------------------------------------------------------
// tWaug [896, 2048]: rows j<768 = tW^T (tW[q,j]), row 768 = bt[q], rows>768 = 0
// ---------------------------------------------------------------------------
__global__ __launch_bounds__(256) void build_tWaug(
    const float* __restrict__ tW, const float* __restrict__ bt,
    bf16_t* __restrict__ out)
{
    __shared__ float t[32][33];
    const int j0 = blockIdx.y * 32, q0 = blockIdx.x * 32;
    const int tx = threadIdx.x, ty = threadIdx.y;
    #pragma unroll
    for (int s = 0; s < 4; ++s) {
        const int q = q0 + ty + s * 8, j = j0 + tx;
        t[ty + s * 8][tx] = (j < Hh) ? tW[(size_t)q * Hh + j] : 0.0f;
    }
    __syncthreads();
    #pragma unroll
    for (int s = 0; s < 4; ++s) {
        const int j = j0 + ty + s * 8, q = q0 + tx;
        float v = t[tx][ty + s * 8];
        if (j == Hh) v = bt[q];
        else if (j > Hh) v = 0.0f;
        out[(size_t)j * Pp + q] = (bf16_t)v;
    }
}

// ---------------------------------------------------------------------------
// hWaug [896, 2112]: rows h<768 = hW^T, row 768 = [bh | 1 @ p=2048], rows>768=0
// ---------------------------------------------------------------------------
__global__ __launch_bounds__(256) void build_hWaug(
    const float* __restrict__ hW, const float* __restrict__ bh,
    bf16_t* __restrict__ out)
{
    __shared__ float t[32][33];
    const int h0 = blockIdx.y * 32, p0 = blockIdx.x * 32;
    const int tx = threadIdx.x, ty = threadIdx.y;
    #pragma unroll
    for (int s = 0; s < 4; ++s) {
        const int p = p0 + ty + s * 8, h = h0 + tx;
        t[ty + s * 8][tx] = (p < Pp && h < Hh) ? hW[(size_t)p * Hh + h] : 0.0f;
    }
    __syncthreads();
    #pragma unroll
    for (int s = 0; s < 4; ++s) {
        const int h = h0 + ty + s * 8, p = p0 + tx;
        float v = t[tx][ty + s * 8];
        if (h == Hh) v = (p < Pp) ? bh[p] : (p == Pp ? 1.0f : 0.0f);
        else if (h > Hh) v = 0.0f;
        out[(size_t)h * KA + p] = (bf16_t)v;
    }
}

// ---------------------------------------------------------------------------
// fill T1taug col stripe [j][2048..2111]: col 2048 = (j==768 ? bil_b[r] : 0)
// ---------------------------------------------------------------------------
__global__ __launch_bounds__(256) void fill_T1cols(
    const float* __restrict__ bil_b, bf16_t* __restrict__ T1)
{
    const int idx = blockIdx.x * 256 + threadIdx.x;
    if (idx >= Rr * HA) return;
    const int r = idx / HA, j = idx % HA;
    bf16_t* p = T1 + (size_t)r * HA * KA + (size_t)j * KA + Pp;
    p[0] = (bf16_t)(j == Hh ? bil_b[r] : 0.0f);
    #pragma unroll
    for (int e = 1; e < 64; ++e) p[e] = (bf16_t)0.0f;
}

// ---------------------------------------------------------------------------
// 128(M)x64(N)-tile NT GEMM, BK=64, A bf16 / B fp32 (in-kernel cvt), dbuf LDS.
// Halving the barrier-drain count vs BK=32 is the point: each __syncthreads
// (vmcnt(0) drain) exposes ~constant L3/HBM latency; BK=64 doubles MFMA per
// drain (16/step) and halves steps (64->32). 4 waves (2x2), wave = 64m x 32n.
//   C[m,n] = sum_k A[m,k] * B[n,k];  T1 = tWaug @ bil_W[r]^T
// grid (N/64, M/128, R).  LDS 64KB -> 2 blocks/CU.
// ---------------------------------------------------------------------------
__global__ __launch_bounds__(256) void gemm_nt_128x64_bf32(
    const bf16_t* __restrict__ A, int lda,
    const float*  __restrict__ B, int ldb, size_t sB,
    bf16_t* __restrict__ C, int ldc, size_t sC, int K)
{
    B += (size_t)blockIdx.z * sB;
    C += (size_t)blockIdx.z * sC;

    __shared__ bf16_t As[2][128 * 64];   // 16 KB per buf
    __shared__ float  Bs[2][64 * 64];    // 16 KB per buf

    const int tid = threadIdx.x;
    const int w = tid >> 6;
    const int l = tid & 63;
    const int m0 = blockIdx.y * 128;
    const int n0 = blockIdx.x * 64;

    // A staging (bf16, 128x64 = 16KB, 4 issues of 32 rows):
    // row = i*32 + w*8 + (l>>3), phys group l&7 -> src col ((l&7)^(l>>3))*8
    const bf16_t* ga = A + (size_t)(m0 + (w << 3) + (l >> 3)) * lda
                         + (((l & 7) ^ (l >> 3)) << 3);
    // B staging (fp32, 64x64 = 16KB, 4 issues of 16 rows):
    // row = i*16 + w*4 + (l>>4); phys 16B-group p = l&15 = kk*8+g;
    // src float col = (p>>3)*32 + ((g ^ (row&7))<<2), row&7 = (w&1)*4 + (l>>4)
    {
    }
    const int br7 = ((w & 1) << 2) | (l >> 4);
    const int p15 = l & 15;
    const float* gb = B + (size_t)(n0 + (w << 2) + (l >> 4)) * ldb
                        + ((p15 >> 3) << 5) + (((p15 & 7) ^ br7) << 2);

    const int wm = (w >> 1) << 6;    // wave M-offset: 0/64
    const int wn = (w & 1) << 5;     // wave N-offset: 0/32
    const int fr = l & 15;
    const int hi = l >> 4;
    const int f7 = fr & 7;

    floatx4 acc[4][2] = {};

    {   // prologue: tile 0
        #pragma unroll
        for (int i = 0; i < 4; ++i) {
            gld_lds16(ga + (size_t)(i * 32) * lda, (char*)As[0] + i * 4096 + (w << 10));
            gld_lds16(gb + (size_t)(i * 16) * ldb, (char*)Bs[0] + i * 4096 + (w << 10));
        }
        ga += 64; gb += 64;
    }

    const int steps = K >> 6;   // 32
    for (int k = 0; k < steps; ++k) {
        __syncthreads();
        const int cur = k & 1;
        if (k + 1 < steps) {
            #pragma unroll
            for (int i = 0; i < 4; ++i) {
                gld_lds16(ga + (size_t)(i * 32) * lda, (char*)As[cur ^ 1] + i * 4096 + (w << 10));
                gld_lds16(gb + (size_t)(i * 16) * ldb, (char*)Bs[cur ^ 1] + i * 4096 + (w << 10));
            }
            ga += 64; gb += 64;
        }

        #pragma unroll
        for (int kk = 0; kk < 2; ++kk) {
            const int aph = ((((kk << 2) + hi) ^ f7) << 3);
            bf16x8 a[4], b[2];
            #pragma unroll
            for (int i = 0; i < 4; ++i)
                a[i] = *(const bf16x8*)&As[cur][(wm + i * 16 + fr) * 64 + aph];
            #pragma unroll
            for (int j = 0; j < 2; ++j) {
                const float* bp = &Bs[cur][(wn + j * 16 + fr) * 64 + (kk << 5)];
                floatx4 x0 = *(const floatx4*)(bp + (((hi << 1) ^ f7) << 2));
                floatx4 x1 = *(const floatx4*)(bp + ((((hi << 1) + 1) ^ f7) << 2));
                #pragma unroll
                for (int e = 0; e < 4; ++e) { b[j][e] = (bf16_t)x0[e]; b[j][e + 4] = (bf16_t)x1[e]; }
            }
            #pragma unroll
            for (int i = 0; i < 4; ++i)
                #pragma unroll
                for (int j = 0; j < 2; ++j)
                    acc[i][j] = __builtin_amdgcn_mfma_f32_16x16x32_bf16(a[i], b[j], acc[i][j], 0, 0, 0);
        }
    }

    const int em = m0 + wm + (hi << 2);
    const int en = n0 + wn + fr;
    #pragma unroll
    for (int i = 0; i < 4; ++i)
        #pragma unroll
        for (int j = 0; j < 2; ++j)
            #pragma unroll
            for (int rg = 0; rg < 4; ++rg)
                C[(size_t)(em + i * 16 + rg) * ldc + en + j * 16] = (bf16_t)acc[i][j][rg];
}

// ---------------------------------------------------------------------------
// 64x64-tile bf16 NT GEMM, BK=64, dbuf LDS (for Bop). 8 MFMA/step, steps=K/64.
// LDS 32KB.
// ---------------------------------------------------------------------------
__global__ __launch_bounds__(256) void gemm_nt_64(
    const bf16_t* __restrict__ A, int lda, size_t sA,
    const bf16_t* __restrict__ B, int ldb, size_t sB,
    bf16_t* __restrict__ C, int ldc, size_t sC, int K)
{
    A += (size_t)blockIdx.z * sA;
    B += (size_t)blockIdx.z * sB;
    C += (size_t)blockIdx.z * sC;

    __shared__ bf16_t As[2][64 * 64];   // 8 KB per buf
    __shared__ bf16_t Bs[2][64 * 64];

    const int tid = threadIdx.x;
    const int w = tid >> 6;
    const int l = tid & 63;
    const int m0 = blockIdx.y * 64;
    const int n0 = blockIdx.x * 64;

    const int srow = (w << 3) + (l >> 3);              // + i*32 per issue
    const int scol = ((l & 7) ^ (l >> 3)) << 3;
    const bf16_t* ga = A + (size_t)(m0 + srow) * lda + scol;
    const bf16_t* gb = B + (size_t)(n0 + srow) * ldb + scol;

    const int wm = (w >> 1) << 5;
    const int wn = (w & 1) << 5;
    const int fr = l & 15;
    const int hi = l >> 4;
    const int f7 = fr & 7;

    floatx4 acc[2][2] = {};

    {
        #pragma unroll
        for (int i = 0; i < 2; ++i) {
            gld_lds16(ga + (size_t)(i * 32) * lda, (char*)As[0] + i * 4096 + (w << 10));
            gld_lds16(gb + (size_t)(i * 32) * ldb, (char*)Bs[0] + i * 4096 + (w << 10));
        }
        ga += 64; gb += 64;
    }

    const int steps = K >> 6;   // 33 for K=2112
    for (int k = 0; k < steps; ++k) {
        __syncthreads();
        const int cur = k & 1;
        if (k + 1 < steps) {
            #pragma unroll
            for (int i = 0; i < 2; ++i) {
                gld_lds16(ga + (size_t)(i * 32) * lda, (char*)As[cur ^ 1] + i * 4096 + (w << 10));
                gld_lds16(gb + (size_t)(i * 32) * ldb, (char*)Bs[cur ^ 1] + i * 4096 + (w << 10));
            }
            ga += 64; gb += 64;
        }

        #pragma unroll
        for (int kk = 0; kk < 2; ++kk) {
            const int ph = ((((kk << 2) + hi) ^ f7) << 3);
            bf16x8 a[2], b[2];
            #pragma unroll
            for (int i = 0; i < 2; ++i) {
                a[i] = *(const bf16x8*)&As[cur][(wm + i * 16 + fr) * 64 + ph];
                b[i] = *(const bf16x8*)&Bs[cur][(wn + i * 16 + fr) * 64 + ph];
            }
            #pragma unroll
            for (int i = 0; i < 2; ++i)
                #pragma unroll
                for (int j = 0; j < 2; ++j)
                    acc[i][j] = __builtin_amdgcn_mfma_f32_16x16x32_bf16(a[i], b[j], acc[i][j], 0, 0, 0);
        }
    }

    const int em = m0 + wm + (hi << 2);
    const int en = n0 + wn + fr;
    #pragma unroll
    for (int i = 0; i < 2; ++i)
        #pragma unroll
        for (int j = 0; j < 2; ++j)
            #pragma unroll
            for (int rg = 0; rg < 4; ++rg)
                C[(size_t)(em + i * 16 + rg) * ldc + en + j * 16] = (bf16_t)acc[i][j][rg];
}

// ---------------------------------------------------------------------------
// 128x128-tile bf16 NT GEMM, BK=64, dbuf LDS (for FG). 32 MFMA/step, steps=14.
// LDS 64KB -> 2 blocks/CU.
// ---------------------------------------------------------------------------
__global__ __launch_bounds__(256) void gemm_nt_128(
    const bf16_t* __restrict__ A, int lda,
    const bf16_t* __restrict__ B, int ldb,
    bf16_t* __restrict__ C, int ldc, int K)
{
    __shared__ bf16_t As[2][128 * 64];   // 16 KB per buf
    __shared__ bf16_t Bs[2][128 * 64];

    const int tid = threadIdx.x;
    const int w = tid >> 6;
    const int l = tid & 63;
    const int m0 = blockIdx.y * 128;
    const int n0 = blockIdx.x * 128;

    const int srow = (w << 3) + (l >> 3);              // + i*32 per issue
    const int scol = ((l & 7) ^ (l >> 3)) << 3;
    const bf16_t* ga = A + (size_t)(m0 + srow) * lda + scol;
    const bf16_t* gb = B + (size_t)(n0 + srow) * ldb + scol;

    const int wm = (w >> 1) << 6;
    const int wn = (w & 1) << 6;
    const int fr = l & 15;
    const int hi = l >> 4;
    const int f7 = fr & 7;

    floatx4 acc[4][4] = {};

    {
        #pragma unroll
        for (int i = 0; i < 4; ++i) {
            gld_lds16(ga + (size_t)(i * 32) * lda, (char*)As[0] + i * 4096 + (w << 10));
            gld_lds16(gb + (size_t)(i * 32) * ldb, (char*)Bs[0] + i * 4096 + (w << 10));
        }
        ga += 64; gb += 64;
    }

    const int steps = K >> 6;   // 14
    for (int k = 0; k < steps; ++k) {
        __syncthreads();
        const int cur = k & 1;
        if (k + 1 < steps) {
            #pragma unroll
            for (int i = 0; i < 4; ++i) {
                gld_lds16(ga + (size_t)(i * 32) * lda, (char*)As[cur ^ 1] + i * 4096 + (w << 10));
                gld_lds16(gb + (size_t)(i * 32) * ldb, (char*)Bs[cur ^ 1] + i * 4096 + (w << 10));
            }
            ga += 64; gb += 64;
        }

        #pragma unroll
        for (int kk = 0; kk < 2; ++kk) {
            const int ph = ((((kk << 2) + hi) ^ f7) << 3);
            bf16x8 a[4], b[4];
            #pragma unroll
            for (int i = 0; i < 4; ++i) {
                a[i] = *(const bf16x8*)&As[cur][(wm + i * 16 + fr) * 64 + ph];
                b[i] = *(const bf16x8*)&Bs[cur][(wn + i * 16 + fr) * 64 + ph];
            }
            #pragma unroll
            for (int i = 0; i < 4; ++i)
                #pragma unroll
                for (int j = 0; j < 4; ++j)
                    acc[i][j] = __builtin_amdgcn_mfma_f32_16x16x32_bf16(a[i], b[j], acc[i][j], 0, 0, 0);
        }
    }

    const int em = m0 + wm + (hi << 2);
    const int en = n0 + wn + fr;
    #pragma unroll
    for (int j = 0; j < 4; ++j) {
        const int n = en + j * 16;
        #pragma unroll
        for (int i = 0; i < 4; ++i) {
            #pragma unroll
            for (int rg = 0; rg < 4; ++rg)
                C[(size_t)(em + i * 16 + rg) * ldc + n] = (bf16_t)(acc[i][j][rg]);
        }
    }
}

// ---------------------------------------------------------------------------
// fused output GEMM, all 3 r per block, BK=64, dbuf LDS. K=896 -> 14 steps.
// 512 threads (8 waves); wave = 32n x 16m; 12 MFMA/step.
//   logits[b,n,m,r] = sum_h FG[b*Nn+n, r*HA+h] * Faug[b*Nn+m, h]
// grid (Nn/64, Nn/64, Bb) = 256 blocks.  LDS 64KB.
// ---------------------------------------------------------------------------
__global__ __launch_bounds__(512) void gemm_out_fused(
    const bf16_t* __restrict__ FG,    // [Mm, JA]
    const bf16_t* __restrict__ FA,    // [Mm, HA]
    float* __restrict__ OUT)
{
    __shared__ bf16_t S[2][4][64 * 64];  // per buf: tiles 0..2 = FG r, 3 = Faug

    const int b = blockIdx.z;
    const int n0 = blockIdx.y * 64;
    const int m0 = blockIdx.x * 64;

    const int tid = threadIdx.x;
    const int w = tid >> 6;      // 0..7
    const int l = tid & 63;

    // staging: 4 issues/step, one 8KB tile per issue over 512 lanes:
    // row = w*8 + (l>>3), phys group l&7 -> src col ((l&7)^(l>>3))*8
    const int srow = (w << 3) + (l >> 3);
    const int scol = ((l & 7) ^ (l >> 3)) << 3;
    const bf16_t* g0 = FG + (size_t)(b * Nn + n0 + srow) * JA + 0 * HA + scol;
    const bf16_t* g1 = FG + (size_t)(b * Nn + n0 + srow) * JA + 1 * HA + scol;
    const bf16_t* g2 = FG + (size_t)(b * Nn + n0 + srow) * JA + 2 * HA + scol;
    const bf16_t* g3 = FA + (size_t)(b * Nn + m0 + srow) * HA + scol;

    const int n_off = (w >> 2) << 5;     // 0/32
    const int m_off = (w & 3) << 4;      // 0/16/32/48
    const int fr = l & 15;
    const int hi = l >> 4;
    const int f7 = fr & 7;

    floatx4 acc[Rr][2] = {};

    {
        char* base = (char*)&S[0][0][0];
        gld_lds16(g0, base + 0 * 8192 + (w << 10));
        gld_lds16(g1, base + 1 * 8192 + (w << 10));
        gld_lds16(g2, base + 2 * 8192 + (w << 10));
        gld_lds16(g3, base + 3 * 8192 + (w << 10));
        g0 += 64; g1 += 64; g2 += 64; g3 += 64;
    }

    constexpr int STEPS = HA / 64; // 14
    for (int k = 0; k < STEPS; ++k) {
        __syncthreads();
        const int cur = k & 1;
        if (k + 1 < STEPS) {
            char* base = (char*)&S[cur ^ 1][0][0];
            gld_lds16(g0, base + 0 * 8192 + (w << 10));
            gld_lds16(g1, base + 1 * 8192 + (w << 10));
            gld_lds16(g2, base + 2 * 8192 + (w << 10));
            gld_lds16(g3, base + 3 * 8192 + (w << 10));
            g0 += 64; g1 += 64; g2 += 64; g3 += 64;
        }

        #pragma unroll
        for (int kk = 0; kk < 2; ++kk) {
            const int ph = ((((kk << 2) + hi) ^ f7) << 3);
            bf16x8 t = *(const bf16x8*)&S[cur][3][(m_off + fr) * 64 + ph];
            #pragma unroll
            for (int r = 0; r < Rr; ++r) {
                #pragma unroll
                for (int i = 0; i < 2; ++i) {
                    bf16x8 a = *(const bf16x8*)&S[cur][r][(n_off + i * 16 + fr) * 64 + ph];
                    acc[r][i] = __builtin_amdgcn_mfma_f32_16x16x32_bf16(a, t, acc[r][i], 0, 0, 0);
                }
            }
        }
    }

    const int en_ = n0 + n_off + (hi << 2);
    const int em_ = m0 + m_off + fr;
    #pragma unroll
    for (int i = 0; i < 2; ++i)
        #pragma unroll
        for (int rg = 0; rg < 4; ++rg) {
            const int n = en_ + i * 16 + rg;
            float* o = OUT + (((size_t)b * Nn + n) * Nn + em_) * Rr;
            #pragma unroll
            for (int r = 0; r < Rr; ++r)
                o[r] = acc[r][i][rg];
        }
}

extern "C" void kernel_launch(void* const* d_in, const int* in_sizes, int n_in,
                              void* d_out, int out_size, void* d_ws, size_t ws_size,
                              hipStream_t stream) {
    const float* features = (const float*)d_in[0]; // [16,256,768]
    const float* head_W   = (const float*)d_in[1]; // [2048,768]
    const float* head_b   = (const float*)d_in[2]; // [2048]
    const float* tail_W   = (const float*)d_in[3]; // [2048,768]
    const float* tail_b   = (const float*)d_in[4]; // [2048]
    const float* bil_W    = (const float*)d_in[5]; // [3,2048,2048]
    const float* bil_b    = (const float*)d_in[6]; // [3]
    float* out = (float*)d_out;                    // [16,256,256,3]

    // workspace layout (bf16), ~42 MB. FG aliases T1taug (dead by step 4).
    char* ws = (char*)d_ws;
    bf16_t* Faug   = (bf16_t*)ws;  ws += (size_t)Mm * HA * 2;       // 7.3 MB
    bf16_t* tWaug  = (bf16_t*)ws;  ws += (size_t)HA * Pp * 2;       // 3.7 MB
    bf16_t* hWaug  = (bf16_t*)ws;  ws += (size_t)HA * KA * 2;       // 3.8 MB
    bf16_t* Bop    = (bf16_t*)ws;  ws += (size_t)Rr * HA * HA * 2;  // 4.8 MB
    bf16_t* T1taug = (bf16_t*)ws;                                   // 11.4 MB
    bf16_t* FG     = T1taug;                                        // 22.0 MB (overlays T1taug)

    // 1) build augmented operands (tiny/streaming; bil_W is consumed fp32-direct)
    build_Faug<<<Mm * (HA / 4) / 256, 256, 0, stream>>>(features, Faug);
    build_tWaug<<<dim3(Pp / 32, HA / 32), dim3(32, 8), 0, stream>>>(tail_W, tail_b, tWaug);
    build_hWaug<<<dim3(KA / 32, HA / 32), dim3(32, 8), 0, stream>>>(head_W, head_b, hWaug);

    // 2) T1taug[r] [896, 2048(+64)] = tWaug [896,2048] @ bil_W[r]^T (B fp32 direct)
    gemm_nt_128x64_bf32<<<dim3(Pp / 64, HA / 128, Rr), 256, 0, stream>>>(
        tWaug, Pp,
        bil_W, Pp, (size_t)Pp * Pp,
        T1taug, KA, (size_t)HA * KA, Pp);
    fill_T1cols<<<(Rr * HA + 255) / 256, 256, 0, stream>>>(bil_b, T1taug);

    // 3) Bop[r] [896, 896] = T1taug[r] [896,2112] @ hWaug^T [896,2112]
    gemm_nt_64<<<dim3(HA / 64, HA / 64, Rr), 256, 0, stream>>>(
        T1taug, KA, (size_t)HA * KA,
        hWaug, KA, 0,
        Bop, HA, (size_t)HA * HA, KA);

    // 4) FG [4096, 2688] = Faug [4096,896] @ Bop^T [2688,896]  (FG overlays T1taug)
    gemm_nt_128<<<dim3(JA / 128, Mm / 128), 256, 0, stream>>>(
        Faug, HA,
        Bop, HA,
        FG, JA, HA);

    // 5) fused output GEMM over all r (K=896, biases already folded in)
    gemm_out_fused<<<dim3(Nn / 64, Nn / 64, Bb), 512, 0, stream>>>(FG, Faug, out);
}

// Round 4
// 253.662 us; speedup vs baseline: 1.2362x; 1.0460x over previous
//
#include <hip/hip_runtime.h>

// Problem constants
constexpr int Bb = 16;      // batch
constexpr int Nn = 256;     // regions
constexpr int Hh = 768;     // hidden
constexpr int Pp = 2048;    // proj dim
constexpr int Rr = 3;       // relation types
constexpr int Mm = Bb * Nn; // 4096 flattened rows
constexpr int HA = 896;     // augmented hidden (768 + 1 bias row + pad)
constexpr int KA = 2080;    // augmented K for Bop GEMM (2048 + 32)
constexpr int JA = Rr * HA; // 2688

typedef __bf16 bf16_t;
typedef __bf16 bf16x8 __attribute__((ext_vector_type(8)));
typedef __bf16 bf16x4 __attribute__((ext_vector_type(4)));
typedef float  floatx4 __attribute__((ext_vector_type(4)));

// async global->LDS, 16B per lane; LDS dest = wave-uniform base + lane*16
__device__ __forceinline__ void gld_lds16(const void* g, void* l) {
    __builtin_amdgcn_global_load_lds(
        (__attribute__((address_space(1))) void*)g,
        (__attribute__((address_space(3))) void*)l,
        16, 0, 0);
}

// ---------------------------------------------------------------------------
// bil_W fp32 [3,2048,2048] -> bf16 (halves T1's dominant staged-byte stream).
// 8 elems/thread: 32B load / 16B store. 6144 blocks x 256 thr, one shot.
// ---------------------------------------------------------------------------
__global__ __launch_bounds__(256) void cvt_bilW(
    const float* __restrict__ in, bf16_t* __restrict__ out)
{
    const size_t i = (size_t)blockIdx.x * 256 + threadIdx.x; // over 3*2048*2048/8
    const float4 v0 = ((const float4*)in)[2 * i];
    const float4 v1 = ((const float4*)in)[2 * i + 1];
    bf16x8 o = { (bf16_t)v0.x, (bf16_t)v0.y, (bf16_t)v0.z, (bf16_t)v0.w,
                 (bf16_t)v1.x, (bf16_t)v1.y, (bf16_t)v1.z, (bf16_t)v1.w };
    ((bf16x8*)out)[i] = o;
}

// ---------------------------------------------------------------------------
// F_aug [4096, 896] bf16: cols 0..767 = F, col 768 = 1, cols 769..895 = 0
// ---------------------------------------------------------------------------
__global__ __launch_bounds__(256) void build_Faug(
    const float* __restrict__ F, bf16_t* __restrict__ out)
{
    const int idx = blockIdx.x * 256 + threadIdx.x;   // over 4096 * (896/4)
    const int n = idx / (HA / 4), c4 = idx % (HA / 4);
    const int h = c4 * 4;
    bf16x4 o;
    if (h < Hh) {
        float4 v = *(const float4*)(F + (size_t)n * Hh + h);
        o = { (bf16_t)v.x, (bf16_t)v.y, (bf16_t)v.z, (bf16_t)v.w };
    } else {
        #pragma unroll
        for (int e = 0; e < 4; ++e) o[e] = (bf16_t)((h + e == Hh) ? 1.0f : 0.0f);
    }
    *(bf16x4*)(out + (size_t)n * HA + h) = o;
}

// ---------------------------------------------------------------------------
// tWaug [896, 2048]: rows j<768 = tW^T (tW[q,j]), row 768 = bt[q], rows>768 = 0
// ---------------------------------------------------------------------------
__global__ __launch_bounds__(256) void build_tWaug(
    const float* __restrict__ tW, const float* __restrict__ bt,
    bf16_t* __restrict__ out)
{
    __shared__ float t[32][33];
    const int j0 = blockIdx.y * 32, q0 = blockIdx.x * 32;
    const int tx = threadIdx.x, ty = threadIdx.y;
    #pragma unroll
    for (int s = 0; s < 4; ++s) {
        const int q = q0 + ty + s * 8, j = j0 + tx;
        t[ty + s * 8][tx] = (j < Hh) ? tW[(size_t)q * Hh + j] : 0.0f;
    }
    __syncthreads();
    #pragma unroll
    for (int s = 0; s < 4; ++s) {
        const int j = j0 + ty + s * 8, q = q0 + tx;
        float v = t[tx][ty + s * 8];
        if (j == Hh) v = bt[q];
        else if (j > Hh) v = 0.0f;
        out[(size_t)j * Pp + q] = (bf16_t)v;
    }
}

// ---------------------------------------------------------------------------
// hWaug [896, 2080]: rows h<768 = hW^T, row 768 = [bh | 1 @ p=2048], rows>768=0
// ---------------------------------------------------------------------------
__global__ __launch_bounds__(256) void build_hWaug(
    const float* __restrict__ hW, const float* __restrict__ bh,
    bf16_t* __restrict__ out)
{
    __shared__ float t[32][33];
    const int h0 = blockIdx.y * 32, p0 = blockIdx.x * 32;
    const int tx = threadIdx.x, ty = threadIdx.y;
    #pragma unroll
    for (int s = 0; s < 4; ++s) {
        const int p = p0 + ty + s * 8, h = h0 + tx;
        t[ty + s * 8][tx] = (p < Pp && h < Hh) ? hW[(size_t)p * Hh + h] : 0.0f;
    }
    __syncthreads();
    #pragma unroll
    for (int s = 0; s < 4; ++s) {
        const int h = h0 + ty + s * 8, p = p0 + tx;
        float v = t[tx][ty + s * 8];
        if (h == Hh) v = (p < Pp) ? bh[p] : (p == Pp ? 1.0f : 0.0f);
        else if (h > Hh) v = 0.0f;
        out[(size_t)h * KA + p] = (bf16_t)v;
    }
}

// ---------------------------------------------------------------------------
// fill T1taug col stripe [j][2048..2079]: col 2048 = (j==768 ? bil_b[r] : 0)
// ---------------------------------------------------------------------------
__global__ __launch_bounds__(256) void fill_T1cols(
    const float* __restrict__ bil_b, bf16_t* __restrict__ T1)
{
    const int idx = blockIdx.x * 256 + threadIdx.x;
    if (idx >= Rr * HA) return;
    const int r = idx / HA, j = idx % HA;
    bf16_t* p = T1 + (size_t)r * HA * KA + (size_t)j * KA + Pp;
    p[0] = (bf16_t)(j == Hh ? bil_b[r] : 0.0f);
    #pragma unroll
    for (int e = 1; e < 32; ++e) p[e] = (bf16_t)0.0f;
}

// ---------------------------------------------------------------------------
// 128(M)x64(N)-tile bf16 NT GEMM, BK=32, dbuf LDS (for T1, B = bf16 bil_W).
// Byte-volume theory: T1 is bound by ~10 TB/s of L2/L3->LDS staging traffic;
// bf16 B halves the B stream (344->172 MB). Round-0 skeleton otherwise.
// 4 waves (2x2), wave = 64m x 32n -> 8 MFMA/step.  LDS 24 KB.
//   C[m,n] = sum_k A[m,k] * B[n,k];  T1 = tWaug @ bilWh[r]^T
// grid (N/64, M/128, R)
// ---------------------------------------------------------------------------
__global__ __launch_bounds__(256) void gemm_nt_128x64(
    const bf16_t* __restrict__ A, int lda,
    const bf16_t* __restrict__ B, int ldb, size_t sB,
    bf16_t* __restrict__ C, int ldc, size_t sC, int K)
{
    B += (size_t)blockIdx.z * sB;
    C += (size_t)blockIdx.z * sC;

    __shared__ bf16_t As[2][128 * 32];   // 8 KB per buf
    __shared__ bf16_t Bs[2][64 * 32];    // 4 KB per buf

    const int tid = threadIdx.x;
    const int w = tid >> 6;
    const int l = tid & 63;
    const int m0 = blockIdx.y * 128;
    const int n0 = blockIdx.x * 64;

    // A staging (bf16, 128x32 = 8KB, 2 issues): row = i*64 + w*16 + l/4
    const bf16_t* ga0 = A + (size_t)(m0 + (w << 4) + (l >> 2)) * lda + ((l & 3) << 3);
    const bf16_t* ga1 = ga0 + (size_t)64 * lda;
    // B staging (bf16, 64x32 = 4KB, 1 issue): row = tid/4, col8 = tid&3;
    // wave w covers rows 16w..16w+15 -> LDS byte base w*1024
    const bf16_t* gb = B + (size_t)(n0 + (tid >> 2)) * ldb + ((tid & 3) << 3);

    const int wm = (w >> 1) << 6;    // wave M-offset: 0/64
    const int wn = (w & 1) << 5;     // wave N-offset: 0/32
    const int fr = l & 15;
    const int fq = (l >> 4) << 3;

    floatx4 acc[4][2] = {};

    {
        gld_lds16(ga0, (char*)As[0] + (w << 10));
        gld_lds16(ga1, (char*)As[0] + 4096 + (w << 10));
        gld_lds16(gb,  (char*)Bs[0] + (w << 10));
        ga0 += 32; ga1 += 32; gb += 32;
    }

    const int steps = K >> 5;   // 64
    for (int k = 0; k < steps; ++k) {
        __syncthreads();
        const int cur = k & 1;
        if (k + 1 < steps) {
            gld_lds16(ga0, (char*)As[cur ^ 1] + (w << 10));
            gld_lds16(ga1, (char*)As[cur ^ 1] + 4096 + (w << 10));
            gld_lds16(gb,  (char*)Bs[cur ^ 1] + (w << 10));
            ga0 += 32; ga1 += 32; gb += 32;
        }

        bf16x8 a[4], b[2];
        #pragma unroll
        for (int i = 0; i < 4; ++i)
            a[i] = *(const bf16x8*)&As[cur][(wm + i * 16 + fr) * 32 + fq];
        #pragma unroll
        for (int j = 0; j < 2; ++j)
            b[j] = *(const bf16x8*)&Bs[cur][(wn + j * 16 + fr) * 32 + fq];
        #pragma unroll
        for (int i = 0; i < 4; ++i)
            #pragma unroll
            for (int j = 0; j < 2; ++j)
                acc[i][j] = __builtin_amdgcn_mfma_f32_16x16x32_bf16(a[i], b[j], acc[i][j], 0, 0, 0);
    }

    const int em = m0 + wm + ((l >> 4) << 2);
    const int en = n0 + wn + (l & 15);
    #pragma unroll
    for (int i = 0; i < 4; ++i)
        #pragma unroll
        for (int j = 0; j < 2; ++j)
            #pragma unroll
            for (int rg = 0; rg < 4; ++rg)
                C[(size_t)(em + i * 16 + rg) * ldc + en + j * 16] = (bf16_t)acc[i][j][rg];
}

// ---------------------------------------------------------------------------
// 64x64-tile bf16 NT GEMM, double-buffered LDS (for Bop)
// ---------------------------------------------------------------------------
__global__ __launch_bounds__(256) void gemm_nt_64(
    const bf16_t* __restrict__ A, int lda, size_t sA,
    const bf16_t* __restrict__ B, int ldb, size_t sB,
    bf16_t* __restrict__ C, int ldc, size_t sC, int K)
{
    A += (size_t)blockIdx.z * sA;
    B += (size_t)blockIdx.z * sB;
    C += (size_t)blockIdx.z * sC;

    __shared__ bf16_t As[2][64 * 32];
    __shared__ bf16_t Bs[2][64 * 32];

    const int tid = threadIdx.x;
    const int w = tid >> 6;
    const int l = tid & 63;
    const int m0 = blockIdx.y * 64;
    const int n0 = blockIdx.x * 64;

    const bf16_t* ga = A + (size_t)(m0 + (tid >> 2)) * lda + ((tid & 3) << 3);
    const bf16_t* gb = B + (size_t)(n0 + (tid >> 2)) * ldb + ((tid & 3) << 3);

    const int wm = (w >> 1) << 5;
    const int wn = (w & 1) << 5;
    const int fr = l & 15;
    const int fq = (l >> 4) << 3;

    floatx4 acc[2][2] = {};

    {
        gld_lds16(ga, (char*)As[0] + (w << 10));
        gld_lds16(gb, (char*)Bs[0] + (w << 10));
        ga += 32; gb += 32;
    }

    const int steps = K >> 5;
    for (int k = 0; k < steps; ++k) {
        __syncthreads();
        const int cur = k & 1;
        if (k + 1 < steps) {
            gld_lds16(ga, (char*)As[cur ^ 1] + (w << 10));
            gld_lds16(gb, (char*)Bs[cur ^ 1] + (w << 10));
            ga += 32; gb += 32;
        }

        bf16x8 a[2], b[2];
        #pragma unroll
        for (int i = 0; i < 2; ++i) {
            a[i] = *(const bf16x8*)&As[cur][(wm + i * 16 + fr) * 32 + fq];
            b[i] = *(const bf16x8*)&Bs[cur][(wn + i * 16 + fr) * 32 + fq];
        }
        #pragma unroll
        for (int i = 0; i < 2; ++i)
            #pragma unroll
            for (int j = 0; j < 2; ++j)
                acc[i][j] = __builtin_amdgcn_mfma_f32_16x16x32_bf16(a[i], b[j], acc[i][j], 0, 0, 0);
    }

    const int em = m0 + wm + ((l >> 4) << 2);
    const int en = n0 + wn + (l & 15);
    #pragma unroll
    for (int i = 0; i < 2; ++i)
        #pragma unroll
        for (int j = 0; j < 2; ++j)
            #pragma unroll
            for (int rg = 0; rg < 4; ++rg)
                C[(size_t)(em + i * 16 + rg) * ldc + en + j * 16] = (bf16_t)acc[i][j][rg];
}

// ---------------------------------------------------------------------------
// 128x128-tile bf16 NT GEMM, double-buffered LDS (for FG)
// ---------------------------------------------------------------------------
__global__ __launch_bounds__(256) void gemm_nt_128(
    const bf16_t* __restrict__ A, int lda,
    const bf16_t* __restrict__ B, int ldb,
    bf16_t* __restrict__ C, int ldc, int K)
{
    __shared__ bf16_t As[2][128 * 32];
    __shared__ bf16_t Bs[2][128 * 32];

    const int tid = threadIdx.x;
    const int w = tid >> 6;
    const int l = tid & 63;
    const int m0 = blockIdx.y * 128;
    const int n0 = blockIdx.x * 128;

    const int srow = (w << 4) + (l >> 2);
    const int scol = (l & 3) << 3;
    const bf16_t* ga0 = A + (size_t)(m0 + srow) * lda + scol;
    const bf16_t* ga1 = ga0 + (size_t)64 * lda;
    const bf16_t* gb0 = B + (size_t)(n0 + srow) * ldb + scol;
    const bf16_t* gb1 = gb0 + (size_t)64 * ldb;

    const int wm = (w >> 1) << 6;
    const int wn = (w & 1) << 6;
    const int fr = l & 15;
    const int fq = (l >> 4) << 3;

    floatx4 acc[4][4] = {};

    {
        char* a = (char*)As[0] + (w << 10);
        char* b = (char*)Bs[0] + (w << 10);
        gld_lds16(ga0, a); gld_lds16(ga1, a + 4096);
        gld_lds16(gb0, b); gld_lds16(gb1, b + 4096);
        ga0 += 32; ga1 += 32; gb0 += 32; gb1 += 32;
    }

    const int steps = K >> 5;
    for (int k = 0; k < steps; ++k) {
        __syncthreads();
        const int cur = k & 1;
        if (k + 1 < steps) {
            char* a = (char*)As[cur ^ 1] + (w << 10);
            char* b = (char*)Bs[cur ^ 1] + (w << 10);
            gld_lds16(ga0, a); gld_lds16(ga1, a + 4096);
            gld_lds16(gb0, b); gld_lds16(gb1, b + 4096);
            ga0 += 32; ga1 += 32; gb0 += 32; gb1 += 32;
        }

        bf16x8 a[4], b[4];
        #pragma unroll
        for (int i = 0; i < 4; ++i) {
            a[i] = *(const bf16x8*)&As[cur][(wm + i * 16 + fr) * 32 + fq];
            b[i] = *(const bf16x8*)&Bs[cur][(wn + i * 16 + fr) * 32 + fq];
        }
        #pragma unroll
        for (int i = 0; i < 4; ++i)
            #pragma unroll
            for (int j = 0; j < 4; ++j)
                acc[i][j] = __builtin_amdgcn_mfma_f32_16x16x32_bf16(a[i], b[j], acc[i][j], 0, 0, 0);
    }

    const int em = m0 + wm + ((l >> 4) << 2);
    const int en = n0 + wn + (l & 15);
    #pragma unroll
    for (int j = 0; j < 4; ++j) {
        const int n = en + j * 16;
        #pragma unroll
        for (int i = 0; i < 4; ++i) {
            #pragma unroll
            for (int rg = 0; rg < 4; ++rg)
                C[(size_t)(em + i * 16 + rg) * ldc + n] = (bf16_t)(acc[i][j][rg]);
        }
    }
}

// ---------------------------------------------------------------------------
// fused output GEMM, all 3 r per block, dbuf LDS, K=896, 512 threads (8 waves
// -> 2 waves/SIMD at 1 block/CU; wave = 32n x 16m, 6 MFMA/step):
//   logits[b,n,m,r] = sum_h FG[b*Nn+n, r*HA+h] * Faug[b*Nn+m, h]
// grid (Nn/64, Nn/64, Bb) = 256 blocks.
// ---------------------------------------------------------------------------
__global__ __launch_bounds__(512) void gemm_out_fused(
    const bf16_t* __restrict__ FG,    // [Mm, JA]
    const bf16_t* __restrict__ FA,    // [Mm, HA]
    float* __restrict__ OUT)
{
    __shared__ bf16_t S[2][4][64 * 32];  // tiles 0..2 = FG r, 3 = Faug (32KB)

    const int b = blockIdx.z;
    const int n0 = blockIdx.y * 64;
    const int m0 = blockIdx.x * 64;

    const int tid = threadIdx.x;
    const int w = tid >> 6;      // 0..7
    const int l = tid & 63;

    // staging: 16KB/step over 512 lanes = 2 issues of 16B.
    // issue i, wave w covers LDS bytes i*8192 + w*1024 + l*16
    //   -> tile = 2i + (w>>2), row = (w&3)*16 + l/4, col8 = (l&3)*8
    const int srow = ((w & 3) << 4) + (l >> 2);
    const int scol = (l & 3) << 3;
    const int t0 = w >> 2;               // issue0 tile: FG r = 0/1
    const bf16_t* g0 = FG + (size_t)(b * Nn + n0 + srow) * JA + t0 * HA + scol;
    const bf16_t* g1 = (t0 == 0)
        ? FG + (size_t)(b * Nn + n0 + srow) * JA + 2 * HA + scol   // tile2: FG r=2
        : FA + (size_t)(b * Nn + m0 + srow) * HA + scol;           // tile3: Faug

    const int n_off = (w >> 2) << 5;     // 0/32
    const int m_off = (w & 3) << 4;      // 0/16/32/48
    const int fr = l & 15;
    const int fq = (l >> 4) << 3;

    floatx4 acc[Rr][2] = {};

    {
        char* base = (char*)&S[0][0][0];
        gld_lds16(g0, base + (w << 10));        g0 += 32;
        gld_lds16(g1, base + 8192 + (w << 10)); g1 += 32;
    }

    constexpr int STEPS = HA / 32; // 28
    for (int k = 0; k < STEPS; ++k) {
        __syncthreads();
        const int cur = k & 1;
        if (k + 1 < STEPS) {
            char* base = (char*)&S[cur ^ 1][0][0];
            gld_lds16(g0, base + (w << 10));        g0 += 32;
            gld_lds16(g1, base + 8192 + (w << 10)); g1 += 32;
        }

        bf16x8 t = *(const bf16x8*)&S[cur][3][(m_off + fr) * 32 + fq];
        #pragma unroll
        for (int r = 0; r < Rr; ++r) {
            #pragma unroll
            for (int i = 0; i < 2; ++i) {
                bf16x8 a = *(const bf16x8*)&S[cur][r][(n_off + i * 16 + fr) * 32 + fq];
                acc[r][i] = __builtin_amdgcn_mfma_f32_16x16x32_bf16(a, t, acc[r][i], 0, 0, 0);
            }
        }
    }

    const int en_ = n0 + n_off + ((l >> 4) << 2);
    const int em_ = m0 + m_off + (l & 15);
    #pragma unroll
    for (int i = 0; i < 2; ++i)
        #pragma unroll
        for (int rg = 0; rg < 4; ++rg) {
            const int n = en_ + i * 16 + rg;
            float* o = OUT + (((size_t)b * Nn + n) * Nn + em_) * Rr;
            #pragma unroll
            for (int r = 0; r < Rr; ++r)
                o[r] = acc[r][i][rg];
        }
}

extern "C" void kernel_launch(void* const* d_in, const int* in_sizes, int n_in,
                              void* d_out, int out_size, void* d_ws, size_t ws_size,
                              hipStream_t stream) {
    const float* features = (const float*)d_in[0]; // [16,256,768]
    const float* head_W   = (const float*)d_in[1]; // [2048,768]
    const float* head_b   = (const float*)d_in[2]; // [2048]
    const float* tail_W   = (const float*)d_in[3]; // [2048,768]
    const float* tail_b   = (const float*)d_in[4]; // [2048]
    const float* bil_W    = (const float*)d_in[5]; // [3,2048,2048]
    const float* bil_b    = (const float*)d_in[6]; // [3]
    float* out = (float*)d_out;                    // [16,256,256,3]

    // workspace layout (bf16), total 52.76 MB — same footprint as round 0.
    // Z region (26.84 MB) is time-shared:
    //   steps 0-2: bilWh (25.17 MB) lives at Z[0..]
    //   step 3+:   Bop (4.82 MB) at Z[0..]   (bilWh dead after T1)
    //   step 4+:   FG (22.02 MB) at Z[4.82MB..]
    char* ws = (char*)d_ws;
    bf16_t* Faug   = (bf16_t*)ws;  ws += (size_t)Mm * HA * 2;       // 7.34 MB
    bf16_t* tWaug  = (bf16_t*)ws;  ws += (size_t)HA * Pp * 2;       // 3.67 MB
    bf16_t* hWaug  = (bf16_t*)ws;  ws += (size_t)HA * KA * 2;       // 3.73 MB
    bf16_t* T1taug = (bf16_t*)ws;  ws += (size_t)Rr * HA * KA * 2;  // 11.18 MB
    char*   Z      = ws;
    bf16_t* bilWh  = (bf16_t*)Z;                                    // 25.17 MB (steps 0-2)
    bf16_t* Bop    = (bf16_t*)Z;                                    // 4.82 MB (step 3+)
    bf16_t* FG     = (bf16_t*)(Z + (size_t)Rr * HA * HA * 2);       // 22.02 MB (step 4+)

    // 0) bil_W -> bf16 (one streaming pass; halves T1's B staging bytes)
    cvt_bilW<<<(Rr * Pp * Pp / 8) / 256, 256, 0, stream>>>(bil_W, bilWh);

    // 1) build augmented operands (tiny/streaming)
    build_Faug<<<Mm * (HA / 4) / 256, 256, 0, stream>>>(features, Faug);
    build_tWaug<<<dim3(Pp / 32, HA / 32), dim3(32, 8), 0, stream>>>(tail_W, tail_b, tWaug);
    build_hWaug<<<dim3(KA / 32, HA / 32), dim3(32, 8), 0, stream>>>(head_W, head_b, hWaug);

    // 2) T1taug[r] [896, 2048(+32)] = tWaug [896,2048] @ bilWh[r]^T (all bf16)
    gemm_nt_128x64<<<dim3(Pp / 64, HA / 128, Rr), 256, 0, stream>>>(
        tWaug, Pp,
        bilWh, Pp, (size_t)Pp * Pp,
        T1taug, KA, (size_t)HA * KA, Pp);
    fill_T1cols<<<(Rr * HA + 255) / 256, 256, 0, stream>>>(bil_b, T1taug);

    // 3) Bop[r] [896, 896] = T1taug[r] [896,2080] @ hWaug^T [896,2080]
    //    (writes over dead bilWh region)
    gemm_nt_64<<<dim3(HA / 64, HA / 64, Rr), 256, 0, stream>>>(
        T1taug, KA, (size_t)HA * KA,
        hWaug, KA, 0,
        Bop, HA, (size_t)HA * HA, KA);

    // 4) FG [4096, 2688] = Faug [4096,896] @ Bop^T [2688,896]
    gemm_nt_128<<<dim3(JA / 128, Mm / 128), 256, 0, stream>>>(
        Faug, HA,
        Bop, HA,
        FG, JA, HA);

    // 5) fused output GEMM over all r (K=896, biases already folded in)
    gemm_out_fused<<<dim3(Nn / 64, Nn / 64, Bb), 512, 0, stream>>>(FG, Faug, out);
}